// Round 6
// baseline (165.408 us; speedup 1.0000x reference)
//
#include <hip/hip_runtime.h>

// (B,N,D,L) = (32,1000,256,3). ALL tensors are FP32 (round-5 probe: the
// "(bf16" in the assert label is hardcoded text; 0x4800-ushort probe read
// back as ~0.0 => fp32 readout; out buffer = 2 x 8,192,000 fp32 = 64 MB).
// Inputs in dict order: d_in[0]=x (unused), d_in[1]=node_feature,
// d_in[2]=Ws, d_in[3]=bs.  Math collapses (A_norm = ones/N):
//   h[b,:] = MLP(mean_n nf[b,n,:]);  out0 = nf + h (broadcast);  out1 = nf.
#define BB 32
#define NN 1000
#define DD 256
#define LL 3
#define SS 25              // node-axis splits for the column mean
#define RPS 40             // rows per split; SS*RPS == NN
#define ELEMS (BB * NN * DD)   // 8,192,000 floats per output tensor

// ---- Kernel 0: zero the column-sum accumulator (d_ws is poisoned 0xAA) ----
__global__ __launch_bounds__(256) void k_zero(float* __restrict__ p) {
    p[blockIdx.x * 256 + threadIdx.x] = 0.f;
}

// ---- Kernel 1: partial column sums over the node axis, fp32 float4 loads ----
// grid (SS, BB), 256 thr. Thread t: row-in-group = t>>6 (4 rows), f4-col = t&63.
__global__ __launch_bounds__(256) void k_colsum(const float* __restrict__ nf,
                                                float* __restrict__ sums) {
    const int s = blockIdx.x, b = blockIdx.y, t = threadIdx.x;
    const int rg = t >> 6, dg = t & 63;
    const float4* src = (const float4*)nf;          // DD/4 = 64 float4 per row
    float4 acc = make_float4(0.f, 0.f, 0.f, 0.f);
#pragma unroll
    for (int c = 0; c < RPS / 4; c++) {             // 10 iters of 4 rows
        const int n = s * RPS + c * 4 + rg;
        float4 v = src[(b * NN + n) * (DD / 4) + dg];
        acc.x += v.x; acc.y += v.y; acc.z += v.z; acc.w += v.w;
    }
    __shared__ float red[1024];
    ((float4*)red)[rg * 64 + dg] = acc;             // red[rg*256 + dg*4 + j]
    __syncthreads();
    float sum = 0.f;
#pragma unroll
    for (int r = 0; r < 4; r++) sum += red[r * 256 + t];  // thread t owns d == t
    atomicAdd(&sums[b * DD + t], sum);              // 25 adders per address
}

// ---- Kernel 2: mean + 3-layer MLP on the (BB x DD) matrix, fp32 ----
// 32 blocks (one per batch), 256 thr. Thread t: kgrp = t>>6 (4 groups of 64 k),
// f4-col = t&63. Per layer: 64 fused k-steps with float4 W loads, 4-way LDS reduce.
__global__ __launch_bounds__(256) void k_mlp(const float* __restrict__ sums,
                                             const float* __restrict__ Ws,
                                             const float* __restrict__ bsv,
                                             float* __restrict__ hrow) {
    const int b = blockIdx.x, t = threadIdx.x;
    __shared__ float h[DD];
    __shared__ float red[1024];
    h[t] = sums[b * DD + t] * (1.0f / (float)NN);
    __syncthreads();
    const int kg = t >> 6, dg = t & 63;
    for (int l = 0; l < LL; l++) {
        const float4* w = (const float4*)(Ws + l * DD * DD);  // W[k][d], row-major
        float4 acc = make_float4(0.f, 0.f, 0.f, 0.f);
#pragma unroll 8
        for (int kk = 0; kk < 64; kk++) {
            const int k = kg * 64 + kk;
            const float hk = h[k];
            float4 v = w[k * (DD / 4) + dg];
            acc.x += hk * v.x; acc.y += hk * v.y;
            acc.z += hk * v.z; acc.w += hk * v.w;
        }
        ((float4*)red)[kg * 64 + dg] = acc;
        __syncthreads();
        float o = 0.f;
#pragma unroll
        for (int r = 0; r < 4; r++) o += red[r * 256 + t];
        o += bsv[l * DD + t];
        if (l < LL - 1) o = fmaxf(o, 0.f);
        __syncthreads();            // all reads of red/h done before overwrite
        h[t] = o;
        __syncthreads();
    }
    hrow[b * DD + t] = h[t];
}

// ---- Kernel 3: out0 = nf + broadcast(h), out1 = nf. float4, fp32 offsets. ----
__global__ __launch_bounds__(256) void k_out(const float* __restrict__ nf,
                                             const float* __restrict__ hrow,
                                             float* __restrict__ out) {
    const int i = blockIdx.x * 256 + threadIdx.x;   // float4-chunk id, 2,048,000
    const int e = i * 4;                            // flat float index
    const int b = e / (NN * DD);
    const int d0 = e & (DD - 1);                    // multiple of 4
    float4 v = ((const float4*)nf)[i];
    float4 hv = *(const float4*)(hrow + b * DD + d0);
    float4 o = make_float4(v.x + hv.x, v.y + hv.y, v.z + hv.z, v.w + hv.w);
    ((float4*)out)[i] = o;                          // output 0: floats [0, 8.192M)
    ((float4*)(out + ELEMS))[i] = v;                // output 1: floats [8.192M, 16.384M)
}

extern "C" void kernel_launch(void* const* d_in, const int* in_sizes, int n_in,
                              void* d_out, int out_size, void* d_ws, size_t ws_size,
                              hipStream_t stream) {
    const float* nf  = (const float*)d_in[1];   // node_feature (dict order)
    const float* Ws  = (const float*)d_in[2];   // (L,D,D)
    const float* bsv = (const float*)d_in[3];   // (L,D) zeros, included anyway
    float* out = (float*)d_out;

    float* sums = (float*)d_ws;                 // BB*DD = 8192 floats
    float* hrow = sums + BB * DD;               // BB*DD = 8192 floats

    k_zero<<<BB * DD / 256, 256, 0, stream>>>(sums);
    k_colsum<<<dim3(SS, BB), 256, 0, stream>>>(nf, sums);
    k_mlp<<<BB, 256, 0, stream>>>(sums, Ws, bsv, hrow);
    k_out<<<(ELEMS / 4) / 256, 256, 0, stream>>>(nf, hrow, out);
}

// Round 7
// 124.824 us; speedup vs baseline: 1.3251x; 1.3251x over previous
//
#include <hip/hip_runtime.h>

// (B,N,D,L) = (32,1000,256,3), all fp32 (established round 5-6).
// d_in: [0]=x (unused), [1]=node_feature, [2]=Ws (L,D,D), [3]=bs (L,D).
// Math collapses (A_norm = ones/N):
//   h[b,:] = MLP(mean_n nf[b,n,:]);  out0 = nf + h (broadcast);  out1 = nf.
//
// R6 post-mortem: monolithic k_mlp (32 blocks) was latency-bound — 75 us,
// VALUBusy 0.24%, occupancy 1.4%. Restructured into 3 per-layer GEMV
// launches with 256 blocks each (one per CU), coalesced W reads, 32-deep ILP.
#define BB 32
#define NN 1000
#define DD 256
#define SS 25              // node-axis splits for the column mean
#define RPS 40             // rows per split; SS*RPS == NN
#define ELEMS (BB * NN * DD)   // 8,192,000 floats per output tensor

// ---- Kernel 0: zero the column-sum accumulator (d_ws is poisoned 0xAA) ----
__global__ __launch_bounds__(256) void k_zero(float* __restrict__ p) {
    p[blockIdx.x * 256 + threadIdx.x] = 0.f;
}

// ---- Kernel 1: partial column sums over the node axis, float4 loads ----
// grid (SS, BB), 256 thr. Thread t: row-in-group = t>>6 (4 rows), f4-col = t&63.
__global__ __launch_bounds__(256) void k_colsum(const float* __restrict__ nf,
                                                float* __restrict__ sums) {
    const int s = blockIdx.x, b = blockIdx.y, t = threadIdx.x;
    const int rg = t >> 6, dg = t & 63;
    const float4* src = (const float4*)nf;          // DD/4 = 64 float4 per row
    float4 acc = make_float4(0.f, 0.f, 0.f, 0.f);
#pragma unroll
    for (int c = 0; c < RPS / 4; c++) {             // 10 iters of 4 rows
        const int n = s * RPS + c * 4 + rg;
        float4 v = src[(b * NN + n) * (DD / 4) + dg];
        acc.x += v.x; acc.y += v.y; acc.z += v.z; acc.w += v.w;
    }
    __shared__ float red[1024];
    ((float4*)red)[rg * 64 + dg] = acc;             // red[rg*256 + dg*4 + j]
    __syncthreads();
    float sum = 0.f;
#pragma unroll
    for (int r = 0; r < 4; r++) sum += red[r * 256 + t];  // thread t owns d == t
    atomicAdd(&sums[b * DD + t], sum);              // 25 adders per address
}

// ---- Kernel 2 (x3 launches): one MLP layer, Hout = act(scale*Hin @ W + b) ----
// grid (8 d-slices, BB). Block: 256 thr = 8 kgroups x 32 dims. Each thread
// accumulates 32 k-steps (coalesced W rows, 32-deep ILP), 8-way LDS reduce.
__global__ __launch_bounds__(256) void k_layer(const float* __restrict__ Hin,
                                               const float* __restrict__ W,
                                               const float* __restrict__ bias,
                                               float* __restrict__ Hout,
                                               float scale, int relu) {
    const int ds = blockIdx.x, b = blockIdx.y, t = threadIdx.x;
    const int kg = t >> 5, dl = t & 31;
    const int d = ds * 32 + dl;
    __shared__ float h[DD];
    __shared__ float red[256];
    h[t] = Hin[b * DD + t] * scale;
    __syncthreads();
    float acc = 0.f;
#pragma unroll
    for (int kk = 0; kk < 32; kk++) {
        const int k = kg * 32 + kk;
        acc += h[k] * W[k * DD + d];    // lanes span d: 128 B coalesced segments
    }
    red[t] = acc;
    __syncthreads();
    if (kg == 0) {
        float o = acc;
#pragma unroll
        for (int r = 1; r < 8; r++) o += red[r * 32 + dl];
        o += bias[d];
        if (relu) o = fmaxf(o, 0.f);
        Hout[b * DD + d] = o;
    }
}

// ---- Kernel 3: out0 = nf + broadcast(h), out1 = nf. float4 everywhere. ----
__global__ __launch_bounds__(256) void k_out(const float* __restrict__ nf,
                                             const float* __restrict__ hrow,
                                             float* __restrict__ out) {
    const int i = blockIdx.x * 256 + threadIdx.x;   // float4-chunk id, 2,048,000
    const int e = i * 4;                            // flat float index
    const int b = e / (NN * DD);
    const int d0 = e & (DD - 1);                    // multiple of 4
    float4 v = ((const float4*)nf)[i];
    float4 hv = *(const float4*)(hrow + b * DD + d0);
    float4 o = make_float4(v.x + hv.x, v.y + hv.y, v.z + hv.z, v.w + hv.w);
    ((float4*)out)[i] = o;                          // output 0
    ((float4*)(out + ELEMS))[i] = v;                // output 1
}

extern "C" void kernel_launch(void* const* d_in, const int* in_sizes, int n_in,
                              void* d_out, int out_size, void* d_ws, size_t ws_size,
                              hipStream_t stream) {
    const float* nf  = (const float*)d_in[1];   // node_feature
    const float* Ws  = (const float*)d_in[2];   // (L,D,D)
    const float* bsv = (const float*)d_in[3];   // (L,D)
    float* out = (float*)d_out;

    float* sums = (float*)d_ws;                 // BB*DD floats
    float* hA   = sums + BB * DD;               // BB*DD floats
    float* hB   = hA   + BB * DD;               // BB*DD floats

    k_zero<<<BB * DD / 256, 256, 0, stream>>>(sums);
    k_colsum<<<dim3(SS, BB), 256, 0, stream>>>(nf, sums);
    // layer 0: mean (scale 1/N) + W0 + b0 + relu
    k_layer<<<dim3(8, BB), 256, 0, stream>>>(sums, Ws + 0 * DD * DD, bsv + 0 * DD,
                                             hA, 1.0f / (float)NN, 1);
    // layer 1: W1 + b1 + relu
    k_layer<<<dim3(8, BB), 256, 0, stream>>>(hA, Ws + 1 * DD * DD, bsv + 1 * DD,
                                             hB, 1.0f, 1);
    // layer 2: W2 + b2 (no relu)
    k_layer<<<dim3(8, BB), 256, 0, stream>>>(hB, Ws + 2 * DD * DD, bsv + 2 * DD,
                                             hA, 1.0f, 0);
    k_out<<<(ELEMS / 4) / 256, 256, 0, stream>>>(nf, hA, out);
}